// Round 6
// baseline (363.964 us; speedup 1.0000x reference)
//
#include <hip/hip_runtime.h>
#include <hip/hip_bf16.h>
#include <math.h>

#define K      128
#define NONE   2048
#define NTWO   64
#define NB2    256            // kernel-2 blocks (8 one-hop rows each)
#define EPSV   1e-12f
#define PADR   132            // padded LDS row length (bank-conflict-free)

// ---- workspace layout (float offsets) ----
#define OFF_TM      0                       // two_mean: 2048*128
#define OFF_WT_C2H  (NONE*K)                // Wc2h^T : 128*128
#define OFF_WT_S2H  (OFF_WT_C2H + K*K)      // Ws2h^T
#define OFF_WT_C1H  (OFF_WT_S2H + K*K)      // Wc1h^T
#define OFF_WT_S1H  (OFF_WT_C1H + K*K)      // Ws1h^T
#define OFF_WT_M    (OFF_WT_S1H + K*K)      // W_mat^T
#define OFF_P       (OFF_WT_M  + K*K)       // partials: NB2*128
// total = 262144 + 5*16384 + 32768 = 376832 floats = 1.44 MB

// ---------------------------------------------------------------------------
// Kernel 1: two-hop gather+mean (blocks 0..2047) + weight transposes (2048..2052)
// ---------------------------------------------------------------------------
__global__ __launch_bounds__(128)
void k1_gather_transpose(const float* __restrict__ emb,
                         const int*   __restrict__ two_hop,
                         const float* __restrict__ Wc2h,
                         const float* __restrict__ Ws2h,
                         const float* __restrict__ Wc1h,
                         const float* __restrict__ Ws1h,
                         const float* __restrict__ Wm,
                         float* __restrict__ ws)
{
    __shared__ int   idxs[NTWO];
    __shared__ __align__(16) float red[4][K];

    const int bid = blockIdx.x;
    const int tid = threadIdx.x;

    if (bid < NONE) {
        if (tid < NTWO) idxs[tid] = two_hop[bid * NTWO + tid];
        __syncthreads();

        const int g  = tid >> 5;      // 4 neighbor-groups of 16 rows
        const int l  = tid & 31;
        const int c0 = l * 4;         // 4 columns per lane (full 512B row / 32 lanes)

        float4 a = make_float4(0.f, 0.f, 0.f, 0.f);
        #pragma unroll
        for (int i = 0; i < 16; ++i) {   // 16 independent loads in flight
            const int n = g + i * 4;
            const float4 e = *(const float4*)&emb[(size_t)idxs[n] * K + c0];
            a.x += e.x; a.y += e.y; a.z += e.z; a.w += e.w;
        }
        *(float4*)&red[g][c0] = a;
        __syncthreads();

        const float sm = red[0][tid] + red[1][tid] + red[2][tid] + red[3][tid];
        ws[OFF_TM + (size_t)bid * K + tid] = sm * (1.f / 64.f);
    } else {
        // transpose one 128x128 matrix: WT[k][j] = W[j][k]
        const int t = bid - NONE;
        const float* src = (t == 0) ? Wc2h : (t == 1) ? Ws2h : (t == 2) ? Wc1h
                         : (t == 3) ? Ws1h : Wm;
        float* dst = ws + ((t == 0) ? OFF_WT_C2H : (t == 1) ? OFF_WT_S2H
                         : (t == 2) ? OFF_WT_C1H : (t == 3) ? OFF_WT_S1H : OFF_WT_M);
        // per-thread sequential 512B reads (L1-line reuse); coalesced writes
        #pragma unroll 4
        for (int k = 0; k < K; ++k)
            dst[k * K + tid] = src[tid * K + k];
    }
}

// ---------------------------------------------------------------------------
// Kernel 2: one_hop_features = l2norm(relu(one_feats@Ws2h^T + two_mean@Wc2h^T + bc2h))
//           emit per-block column sums (deterministic partials, no atomics)
// 256 blocks x 512 threads. Wave w owns output-col slice [w*16, w*16+16).
// Lane split: h=lane>>5 (k-half), r=(lane>>2)&7 (row), qd=lane&3 (col quad).
// Weights are read ONCE per block (128KB) instead of once per wave (1MB).
// ---------------------------------------------------------------------------
__global__ __launch_bounds__(512)
void k2_conv2h(const float* __restrict__ emb,
               const int*   __restrict__ one_hop,
               const float* __restrict__ bc2h,
               float* __restrict__ ws)
{
    const int bid  = blockIdx.x;
    const int tid  = threadIdx.x;
    const int w    = tid >> 6;        // wave 0..7
    const int lane = tid & 63;
    const int h    = lane >> 5;       // k-half (0/1)
    const int r    = (lane >> 2) & 7; // one-hop row within block
    const int qd   = lane & 3;        // col quad
    const int c0   = w * 16 + qd * 4; // 4 output cols
    const int k0   = h * 64;

    __shared__ int onei[8];
    __shared__ __align__(16) float XF[8][PADR];  // one-hop features
    __shared__ __align__(16) float MM[8][PADR];  // two_mean rows
    __shared__ __align__(16) float H [8][PADR];  // relu'd pre-norm rows
    __shared__ float SCL[8];

    if (tid < 8) onei[tid] = one_hop[bid * 8 + tid];
    __syncthreads();

    {   // stage 8 feature rows + 8 mean rows: 512 threads x one float4 each
        const int sr  = tid >> 5;         // 0..15
        const int pos = (tid & 31) * 4;   // 0..124
        if (sr < 8)
            *(float4*)&XF[sr][pos] =
                *(const float4*)&emb[(size_t)onei[sr] * K + pos];
        else
            *(float4*)&MM[sr - 8][pos] =
                *(const float4*)&ws[OFF_TM + (size_t)(bid * 8 + (sr - 8)) * K + pos];
    }
    __syncthreads();

    const float* WsT = ws + OFF_WT_S2H;
    const float* WcT = ws + OFF_WT_C2H;

    float4 a = make_float4(0.f, 0.f, 0.f, 0.f);
    #pragma unroll 4
    for (int i = 0; i < 64; i += 4) {
        const int k = k0 + i;
        const float4 xv = *(const float4*)&XF[r][k];   // 2-way max bank alias
        const float4 mv = *(const float4*)&MM[r][k];
        #pragma unroll
        for (int j = 0; j < 4; ++j) {
            const float  xs = (j == 0) ? xv.x : (j == 1) ? xv.y : (j == 2) ? xv.z : xv.w;
            const float  ms = (j == 0) ? mv.x : (j == 1) ? mv.y : (j == 2) ? mv.z : mv.w;
            const float4 sv = *(const float4*)&WsT[(k + j) * K + c0];
            const float4 cv = *(const float4*)&WcT[(k + j) * K + c0];
            a.x += xs * sv.x + ms * cv.x;
            a.y += xs * sv.y + ms * cv.y;
            a.z += xs * sv.z + ms * cv.z;
            a.w += xs * sv.w + ms * cv.w;
        }
    }

    // fold the two k-halves (lane <-> lane+32 have identical (r,qd))
    a.x += __shfl_xor(a.x, 32, 64);
    a.y += __shfl_xor(a.y, 32, 64);
    a.z += __shfl_xor(a.z, 32, 64);
    a.w += __shfl_xor(a.w, 32, 64);

    if (h == 0) {
        const float4 bb = *(const float4*)&bc2h[c0];
        H[r][c0 + 0] = fmaxf(a.x + bb.x, 0.f);
        H[r][c0 + 1] = fmaxf(a.y + bb.y, 0.f);
        H[r][c0 + 2] = fmaxf(a.z + bb.z, 0.f);
        H[r][c0 + 3] = fmaxf(a.w + bb.w, 0.f);
    }
    __syncthreads();

    // per-row l2 norm scale: wave w handles row w
    {
        const float h0 = H[w][lane];
        const float h1 = H[w][lane + 64];
        float sq = h0 * h0 + h1 * h1;
        #pragma unroll
        for (int m = 1; m <= 32; m <<= 1) sq += __shfl_xor(sq, m, 64);
        if (lane == 0) SCL[w] = 1.f / fmaxf(sqrtf(sq), EPSV);
    }
    __syncthreads();

    // column sums of the normalized rows -> deterministic partials
    if (tid < K) {
        float s = 0.f;
        #pragma unroll
        for (int rr = 0; rr < 8; ++rr) s += H[rr][tid] * SCL[rr];
        ws[OFF_P + bid * K + tid] = s;
    }
}

// ---------------------------------------------------------------------------
// Kernel 3: one_mean reduce -> ego conv -> dW_T -> softmax/att/out
// single block x 512 threads: c = tid&127 (column), q = tid>>7 (4-way split)
// ---------------------------------------------------------------------------
__global__ __launch_bounds__(512)
void k3_final(const float* __restrict__ emb,
              const int*   __restrict__ v,
              const float* __restrict__ bc1h,
              const float* __restrict__ w_d,
              const float* __restrict__ w_W,
              const float* __restrict__ Wm,
              const float* __restrict__ ws,
              float* __restrict__ out)
{
    __shared__ float S[K * K];        // 64 KB score/exp buffer
    __shared__ float X0[K], OM[K], XL[K], DWT[K];
    __shared__ float Q[4][K];         // 4-way combine buffer
    __shared__ float RED[2];

    const int tid = threadIdx.x;      // 0..511
    const int c   = tid & 127;        // column index (k')
    const int q   = tid >> 7;         // quarter 0..3

    // ---- phase 0: one_mean partial reduce (4-way over partial blocks) ----
    const float* P = ws + OFF_P;
    float s = 0.f;
    #pragma unroll 8
    for (int b = q * 64; b < q * 64 + 64; ++b) s += P[b * K + c];
    Q[q][c] = s;
    if (tid < K) X0[tid] = emb[(size_t)v[0] * K + tid];
    __syncthreads();
    if (tid < K)
        OM[tid] = (Q[0][tid] + Q[1][tid] + Q[2][tid] + Q[3][tid]) * (1.f / 2048.f);
    __syncthreads();

    // ---- phase 1: ego conv (k-contraction split 4-way) ----
    const float* WsT1 = ws + OFF_WT_S1H;
    const float* WcT1 = ws + OFF_WT_C1H;
    float acc = 0.f;
    #pragma unroll 4
    for (int k = q * 32; k < q * 32 + 32; ++k)
        acc += X0[k] * WsT1[k * K + c] + OM[k] * WcT1[k * K + c];
    Q[q][c] = acc;
    __syncthreads();

    float r_ = 0.f;
    if (tid < K) {
        const float a = Q[0][tid] + Q[1][tid] + Q[2][tid] + Q[3][tid] + bc1h[tid];
        r_ = fmaxf(a, 0.f);
        float sq = r_ * r_;
        #pragma unroll
        for (int m = 1; m <= 32; m <<= 1) sq += __shfl_xor(sq, m, 64);
        if ((tid & 63) == 0) RED[tid >> 6] = sq;
    }
    __syncthreads();
    if (tid < K) {
        const float tot = RED[0] + RED[1];
        XL[tid] = r_ / fmaxf(sqrtf(tot), EPSV);   // x after one-hop conv
    }
    __syncthreads();

    // ---- phase 2: DWT[j] = w_d*w_W * sum_k x[k]*Wm[j,k] (k split 4-way) ----
    const float* WmT = ws + OFF_WT_M;
    float a2 = 0.f;
    #pragma unroll 4
    for (int k = q * 32; k < q * 32 + 32; ++k)
        a2 += XL[k] * WmT[k * K + c];
    Q[q][c] = a2;
    __syncthreads();
    if (tid < K)
        DWT[tid] = w_d[0] * w_W[0] * (Q[0][tid] + Q[1][tid] + Q[2][tid] + Q[3][tid]);
    __syncthreads();

    // ---- phase 3: per-column softmax over j (each thread owns 32 j's) ----
    // scores[j,c] = DWT[c] * Wm[j,c]; Wm[j*K+c] is COALESCED across lanes (c minor)
    const float dk = DWT[c];
    const float xv = XL[c];
    const int   j0 = q * 32;

    float mx = -INFINITY;
    #pragma unroll 4
    for (int j = j0; j < j0 + 32; ++j) {
        const float sv = dk * Wm[j * K + c];
        S[j * K + c] = sv;
        mx = fmaxf(mx, sv);
    }
    Q[q][c] = mx;
    __syncthreads();
    const float M = fmaxf(fmaxf(Q[0][c], Q[1][c]), fmaxf(Q[2][c], Q[3][c]));
    __syncthreads();                    // Q reads done before overwrite

    float sm = 0.f;
    #pragma unroll 4
    for (int j = j0; j < j0 + 32; ++j) {
        const float e = expf(S[j * K + c] - M);
        S[j * K + c] = e;
        sm += e;
    }
    Q[q][c] = sm;
    __syncthreads();
    const float SUM = Q[0][c] + Q[1][c] + Q[2][c] + Q[3][c];
    const float inv = xv / SUM;         // x[k'] * (1/denominator) fused
    __syncthreads();                    // Q reads done before overwrite

    float s2 = 0.f;
    #pragma unroll 4
    for (int j = j0; j < j0 + 32; ++j) {
        const float o = S[j * K + c] * inv;
        s2 += o * o;
    }
    Q[q][c] = s2;
    __syncthreads();
    const float scn =
        1.f / fmaxf(sqrtf(Q[0][c] + Q[1][c] + Q[2][c] + Q[3][c]), EPSV);

    #pragma unroll 4
    for (int j = j0; j < j0 + 32; ++j)
        out[j * K + c] = S[j * K + c] * inv * scn;
}

// ---------------------------------------------------------------------------
extern "C" void kernel_launch(void* const* d_in, const int* in_sizes, int n_in,
                              void* d_out, int out_size, void* d_ws, size_t ws_size,
                              hipStream_t stream)
{
    const float* emb     = (const float*)d_in[0];
    const float* Wc2h    = (const float*)d_in[1];
    const float* bc2h    = (const float*)d_in[2];
    const float* Ws2h    = (const float*)d_in[3];
    const float* Wc1h    = (const float*)d_in[4];
    const float* bc1h    = (const float*)d_in[5];
    const float* Ws1h    = (const float*)d_in[6];
    const float* w_d     = (const float*)d_in[7];
    const float* w_W     = (const float*)d_in[8];
    const float* Wm      = (const float*)d_in[9];
    const int*   v       = (const int*)d_in[10];
    const int*   one_hop = (const int*)d_in[11];
    const int*   two_hop = (const int*)d_in[12];
    float*       out     = (float*)d_out;
    float*       ws      = (float*)d_ws;

    // k1: 2048 gather blocks + 5 transpose blocks
    hipLaunchKernelGGL(k1_gather_transpose, dim3(NONE + 5), dim3(128), 0, stream,
                       emb, two_hop, Wc2h, Ws2h, Wc1h, Ws1h, Wm, ws);
    // k2: two-hop conv + column partials (weights read once per block)
    hipLaunchKernelGGL(k2_conv2h, dim3(NB2), dim3(512), 0, stream,
                       emb, one_hop, bc2h, ws);
    // k3: final small fused stage
    hipLaunchKernelGGL(k3_final, dim3(1), dim3(512), 0, stream,
                       emb, v, bc1h, w_d, w_W, Wm, ws, out);
}

// Round 7
// 343.503 us; speedup vs baseline: 1.0596x; 1.0596x over previous
//
#include <hip/hip_runtime.h>
#include <hip/hip_bf16.h>
#include <math.h>

#define K      128
#define NONE   2048
#define NTWO   64
#define NB     256            // fused-kernel blocks (8 one-hop rows each)
#define EPSV   1e-12f
#define PADR   132            // padded LDS row length (132 mod 32 = 4 -> <=2-way alias)

// ws layout: partials NB*K floats at offset 0 (only ws use)

// ---------------------------------------------------------------------------
// Fused kernel: per block, 8 one-hop rows:
//   two-hop gather+mean (64 rows each) -> LDS
//   conv l2norm(relu(XF@Ws^T + MM@Wc^T + bc)) with k-tiled LDS weight staging
//   -> per-block column sums (deterministic partials)
// 256 blocks x 512 threads. Wave w owns row w for gather; conv: wave w owns
// output-col slice [w*16,w*16+16), lanes (h=k-half, r=row, qd=col-quad).
// ---------------------------------------------------------------------------
__global__ __launch_bounds__(512)
void k12_fused(const float* __restrict__ emb,
               const int*   __restrict__ one_hop,
               const int*   __restrict__ two_hop,
               const float* __restrict__ Ws2h,
               const float* __restrict__ Wc2h,
               const float* __restrict__ bc2h,
               float* __restrict__ ws)
{
    const int bid  = blockIdx.x;
    const int tid  = threadIdx.x;
    const int w    = tid >> 6;        // wave 0..7
    const int lane = tid & 63;

    __shared__ int SIDX[8][NTWO];
    __shared__ __align__(16) float XF[8][PADR];   // one-hop feature rows
    __shared__ __align__(16) float MM[8][PADR];   // two-hop mean rows
    __shared__ __align__(16) float H [8][PADR];   // relu'd pre-norm rows
    __shared__ __align__(16) float SW[16][PADR];  // Ws k-tile, [kk][c]
    __shared__ __align__(16) float CW[16][PADR];  // Wc k-tile, [kk][c]
    __shared__ float SCL[8];

    const int R = bid * 8 + w;        // this wave's one-hop row

    // ---- phase G: indices + gather + mean ----
    SIDX[w][lane] = two_hop[R * NTWO + lane];

    const int g  = lane >> 5;         // 0/1: even/odd two-hop rows
    const int c0 = (lane & 31) * 4;   // 4 cols per lane

    // ego one-hop feature row (independent load, issued early)
    const int oneIdx = one_hop[R];
    float4 ego = make_float4(0.f, 0.f, 0.f, 0.f);
    if (g == 0)
        ego = *(const float4*)&emb[(size_t)oneIdx * K + c0];

    __syncthreads();                  // SIDX ready

    float4 a = make_float4(0.f, 0.f, 0.f, 0.f);
    #pragma unroll
    for (int i = 0; i < 32; ++i) {    // 32 independent gathers in flight
        const int row = SIDX[w][g + 2 * i];
        const float4 e = *(const float4*)&emb[(size_t)row * K + c0];
        a.x += e.x; a.y += e.y; a.z += e.z; a.w += e.w;
    }
    // fold even/odd halves (lane <-> lane+32 share c0)
    a.x += __shfl_xor(a.x, 32, 64);
    a.y += __shfl_xor(a.y, 32, 64);
    a.z += __shfl_xor(a.z, 32, 64);
    a.w += __shfl_xor(a.w, 32, 64);

    if (g == 0) {
        *(float4*)&XF[w][c0] = ego;
        const float inv64 = 1.f / 64.f;
        MM[w][c0 + 0] = a.x * inv64;
        MM[w][c0 + 1] = a.y * inv64;
        MM[w][c0 + 2] = a.z * inv64;
        MM[w][c0 + 3] = a.w * inv64;
    }
    __syncthreads();                  // XF/MM ready for all rows

    // ---- phase C: conv with k-tiled weight staging ----
    const int h  = lane >> 5;         // k-half within tile
    const int r  = (lane >> 2) & 7;   // one-hop row
    const int qd = lane & 3;          // col quad
    const int cc = w * 16 + qd * 4;   // 4 output cols

    const int sc = tid >> 2;          // staging: col 0..127
    const int q4 = tid & 3;           // staging: k-quad

    float4 acc = make_float4(0.f, 0.f, 0.f, 0.f);

    for (int t = 0; t < 8; ++t) {     // 16-k tiles
        {   // stage Ws/Wc[:, t*16..t*16+16) transposed into SW/CW
            const float4 sv = *(const float4*)&Ws2h[(size_t)sc * K + t * 16 + q4 * 4];
            const float4 cv = *(const float4*)&Wc2h[(size_t)sc * K + t * 16 + q4 * 4];
            SW[q4 * 4 + 0][sc] = sv.x; SW[q4 * 4 + 1][sc] = sv.y;
            SW[q4 * 4 + 2][sc] = sv.z; SW[q4 * 4 + 3][sc] = sv.w;
            CW[q4 * 4 + 0][sc] = cv.x; CW[q4 * 4 + 1][sc] = cv.y;
            CW[q4 * 4 + 2][sc] = cv.z; CW[q4 * 4 + 3][sc] = cv.w;
        }
        __syncthreads();

        #pragma unroll
        for (int j2 = 0; j2 < 2; ++j2) {
            const int kb = h * 8 + j2 * 4;              // tile-local k base
            const float4 xv = *(const float4*)&XF[r][t * 16 + kb];
            const float4 mv = *(const float4*)&MM[r][t * 16 + kb];
            #pragma unroll
            for (int jj = 0; jj < 4; ++jj) {
                const float xs = (jj == 0) ? xv.x : (jj == 1) ? xv.y : (jj == 2) ? xv.z : xv.w;
                const float ms = (jj == 0) ? mv.x : (jj == 1) ? mv.y : (jj == 2) ? mv.z : mv.w;
                const float4 sv = *(const float4*)&SW[kb + jj][cc];
                const float4 cv = *(const float4*)&CW[kb + jj][cc];
                acc.x += xs * sv.x + ms * cv.x;
                acc.y += xs * sv.y + ms * cv.y;
                acc.z += xs * sv.z + ms * cv.z;
                acc.w += xs * sv.w + ms * cv.w;
            }
        }
        __syncthreads();              // SW/CW reads done before next stage
    }

    // fold the two k-halves (lane <-> lane+32 share (r,qd))
    acc.x += __shfl_xor(acc.x, 32, 64);
    acc.y += __shfl_xor(acc.y, 32, 64);
    acc.z += __shfl_xor(acc.z, 32, 64);
    acc.w += __shfl_xor(acc.w, 32, 64);

    if (h == 0) {
        const float4 bb = *(const float4*)&bc2h[cc];
        H[r][cc + 0] = fmaxf(acc.x + bb.x, 0.f);
        H[r][cc + 1] = fmaxf(acc.y + bb.y, 0.f);
        H[r][cc + 2] = fmaxf(acc.z + bb.z, 0.f);
        H[r][cc + 3] = fmaxf(acc.w + bb.w, 0.f);
    }
    __syncthreads();

    // ---- phase N: per-row l2 scale (wave w <-> row w) ----
    {
        const float h0 = H[w][lane];
        const float h1 = H[w][lane + 64];
        float sq = h0 * h0 + h1 * h1;
        #pragma unroll
        for (int m = 1; m <= 32; m <<= 1) sq += __shfl_xor(sq, m, 64);
        if (lane == 0) SCL[w] = 1.f / fmaxf(sqrtf(sq), EPSV);
    }
    __syncthreads();

    // column sums of normalized rows -> deterministic partials
    if (tid < K) {
        float s = 0.f;
        #pragma unroll
        for (int rr = 0; rr < 8; ++rr) s += H[rr][tid] * SCL[rr];
        ws[bid * K + tid] = s;
    }
}

// ---------------------------------------------------------------------------
// Kernel 3: one_mean reduce -> ego conv -> dW_T -> softmax/att/out
// single block x 512 threads: c = tid&127 (column), q = tid>>7 (4-way split)
// Weights read RAW (row-major): per-thread contiguous 128B float4 runs.
// ---------------------------------------------------------------------------
__global__ __launch_bounds__(512)
void k3_final(const float* __restrict__ emb,
              const int*   __restrict__ v,
              const float* __restrict__ Ws1h,
              const float* __restrict__ Wc1h,
              const float* __restrict__ bc1h,
              const float* __restrict__ w_d,
              const float* __restrict__ w_W,
              const float* __restrict__ Wm,
              const float* __restrict__ ws,
              float* __restrict__ out)
{
    __shared__ float S[K * K];        // 64 KB score/exp buffer
    __shared__ float X0[K], OM[K], XL[K], DWT[K];
    __shared__ float Q[4][K];         // 4-way combine buffer
    __shared__ float RED[2];

    const int tid = threadIdx.x;      // 0..511
    const int c   = tid & 127;        // column / row-owner index
    const int q   = tid >> 7;         // quarter 0..3

    // ---- phase 0: one_mean partial reduce (4-way over partial blocks) ----
    const float* P = ws;
    float s = 0.f;
    #pragma unroll 8
    for (int b = q * 64; b < q * 64 + 64; ++b) s += P[b * K + c];
    Q[q][c] = s;
    if (tid < K) X0[tid] = emb[(size_t)v[0] * K + tid];
    __syncthreads();
    if (tid < K)
        OM[tid] = (Q[0][tid] + Q[1][tid] + Q[2][tid] + Q[3][tid]) * (1.f / 2048.f);
    __syncthreads();

    // ---- phase 1: ego conv, raw weights: thread c reads W[c][k] contiguous ----
    {
        const float* Wsr = Ws1h + (size_t)c * K + q * 32;
        const float* Wcr = Wc1h + (size_t)c * K + q * 32;
        float acc = 0.f;
        #pragma unroll
        for (int kk = 0; kk < 32; kk += 4) {
            const float4 sv = *(const float4*)&Wsr[kk];
            const float4 cv = *(const float4*)&Wcr[kk];
            const int k = q * 32 + kk;
            acc += X0[k+0]*sv.x + X0[k+1]*sv.y + X0[k+2]*sv.z + X0[k+3]*sv.w
                 + OM[k+0]*cv.x + OM[k+1]*cv.y + OM[k+2]*cv.z + OM[k+3]*cv.w;
        }
        Q[q][c] = acc;
    }
    __syncthreads();

    float r_ = 0.f;
    if (tid < K) {
        const float a = Q[0][tid] + Q[1][tid] + Q[2][tid] + Q[3][tid] + bc1h[tid];
        r_ = fmaxf(a, 0.f);
        float sq = r_ * r_;
        #pragma unroll
        for (int m = 1; m <= 32; m <<= 1) sq += __shfl_xor(sq, m, 64);
        if ((tid & 63) == 0) RED[tid >> 6] = sq;
    }
    __syncthreads();
    if (tid < K) {
        const float tot = RED[0] + RED[1];
        XL[tid] = r_ / fmaxf(sqrtf(tot), EPSV);   // x after one-hop conv
    }
    __syncthreads();

    // ---- phase 2: DWT[j] = w_d*w_W * sum_k x[k]*Wm[j,k] (raw rows) ----
    {
        const float* Wmr = Wm + (size_t)c * K + q * 32;
        float a2 = 0.f;
        #pragma unroll
        for (int kk = 0; kk < 32; kk += 4) {
            const float4 wv = *(const float4*)&Wmr[kk];
            const int k = q * 32 + kk;
            a2 += XL[k+0]*wv.x + XL[k+1]*wv.y + XL[k+2]*wv.z + XL[k+3]*wv.w;
        }
        Q[q][c] = a2;
    }
    __syncthreads();
    if (tid < K)
        DWT[tid] = w_d[0] * w_W[0] * (Q[0][tid] + Q[1][tid] + Q[2][tid] + Q[3][tid]);
    __syncthreads();

    // ---- phase 3: per-column softmax over j (each thread owns 32 j's) ----
    // scores[j,c] = DWT[c] * Wm[j,c]; Wm[j*K+c] is coalesced across lanes
    const float dk = DWT[c];
    const float xv = XL[c];
    const int   j0 = q * 32;

    float mx = -INFINITY;
    #pragma unroll 4
    for (int j = j0; j < j0 + 32; ++j) {
        const float sv = dk * Wm[j * K + c];
        S[j * K + c] = sv;
        mx = fmaxf(mx, sv);
    }
    Q[q][c] = mx;
    __syncthreads();
    const float M = fmaxf(fmaxf(Q[0][c], Q[1][c]), fmaxf(Q[2][c], Q[3][c]));
    __syncthreads();                    // Q reads done before overwrite

    float sm = 0.f;
    #pragma unroll 4
    for (int j = j0; j < j0 + 32; ++j) {
        const float e = expf(S[j * K + c] - M);
        S[j * K + c] = e;
        sm += e;
    }
    Q[q][c] = sm;
    __syncthreads();
    const float SUM = Q[0][c] + Q[1][c] + Q[2][c] + Q[3][c];
    const float inv = xv / SUM;         // x[k'] * (1/denominator) fused
    __syncthreads();                    // Q reads done before overwrite

    float s2 = 0.f;
    #pragma unroll 4
    for (int j = j0; j < j0 + 32; ++j) {
        const float o = S[j * K + c] * inv;
        s2 += o * o;
    }
    Q[q][c] = s2;
    __syncthreads();
    const float scn =
        1.f / fmaxf(sqrtf(Q[0][c] + Q[1][c] + Q[2][c] + Q[3][c]), EPSV);

    #pragma unroll 4
    for (int j = j0; j < j0 + 32; ++j)
        out[j * K + c] = S[j * K + c] * inv * scn;
}

// ---------------------------------------------------------------------------
extern "C" void kernel_launch(void* const* d_in, const int* in_sizes, int n_in,
                              void* d_out, int out_size, void* d_ws, size_t ws_size,
                              hipStream_t stream)
{
    const float* emb     = (const float*)d_in[0];
    const float* Wc2h    = (const float*)d_in[1];
    const float* bc2h    = (const float*)d_in[2];
    const float* Ws2h    = (const float*)d_in[3];
    const float* Wc1h    = (const float*)d_in[4];
    const float* bc1h    = (const float*)d_in[5];
    const float* Ws1h    = (const float*)d_in[6];
    const float* w_d     = (const float*)d_in[7];
    const float* w_W     = (const float*)d_in[8];
    const float* Wm      = (const float*)d_in[9];
    const int*   v       = (const int*)d_in[10];
    const int*   one_hop = (const int*)d_in[11];
    const int*   two_hop = (const int*)d_in[12];
    float*       out     = (float*)d_out;
    float*       ws      = (float*)d_ws;

    // fused gather+mean+conv -> partials
    hipLaunchKernelGGL(k12_fused, dim3(NB), dim3(512), 0, stream,
                       emb, one_hop, two_hop, Ws2h, Wc2h, bc2h, ws);
    // final small fused stage
    hipLaunchKernelGGL(k3_final, dim3(1), dim3(512), 0, stream,
                       emb, v, Ws1h, Wc1h, bc1h, w_d, w_W, Wm, ws, out);
}